// Round 9
// baseline (662.480 us; speedup 1.0000x reference)
//
#include <hip/hip_runtime.h>
#include <math.h>

#define NN 20000
#define NE 320000
#define DIM 256

typedef __bf16 bf16x8 __attribute__((ext_vector_type(8)));
typedef float f32x4 __attribute__((ext_vector_type(4)));
typedef int i32x4 __attribute__((ext_vector_type(4)));
typedef unsigned short u16x4 __attribute__((ext_vector_type(4)));

union B8 { i32x4 i; bf16x8 b; };

__device__ __forceinline__ unsigned short f2bf(float f) {
  unsigned int u; __builtin_memcpy(&u, &f, 4);
  u += 0x7fffu + ((u >> 16) & 1u);
  return (unsigned short)(u >> 16);
}
__device__ __forceinline__ float bf2f(unsigned short h) {
  unsigned int u = ((unsigned int)h) << 16;
  float f; __builtin_memcpy(&f, &u, 4);
  return f;
}

// Pack one f32 [256][256] weight (row-major W[j_out][k]) into MFMA fragment order, bf16.
__global__ __launch_bounds__(256) void pack_w(const float* __restrict__ W,
                                              unsigned short* __restrict__ wf) {
  int t = blockIdx.x * 256 + threadIdx.x;    // 0..8191
  int lane = t & 63, ct = (t >> 6) & 15, ks = t >> 10;
  int col = ct * 16 + (lane & 15);
  int k0 = ks * 32 + (lane >> 4) * 8;
  const float* src = W + col * 256 + k0;
  unsigned int h[8];
#pragma unroll
  for (int j = 0; j < 8; j++) h[j] = f2bf(src[j]);
  i32x4 v;
  v.x = (int)(h[0] | (h[1] << 16));
  v.y = (int)(h[2] | (h[3] << 16));
  v.z = (int)(h[4] | (h[5] << 16));
  v.w = (int)(h[6] | (h[7] << 16));
  ((i32x4*)wf)[t] = v;
}

// zprep v3: COALESCED reads. Block = 16 edges (one bt-group of a 64-edge tile).
// Lanes read contiguous 1KB rows of ea and x[dst]; product staged to an 8KB LDS
// fragment tile; phase B writes the tile out linearly (fragment order).
// Output: tile t (64 edges) occupies [t*64KB, t*64KB+32KB) of zg; frag (ks,bt)
// is the 1KB chunk at (ks*4+bt)*1024, holding lanes (rq*16+cl)*16B.
__global__ __launch_bounds__(256) void zprep(const float* __restrict__ x,
                                             const int* __restrict__ ei,
                                             const float* __restrict__ ea,
                                             unsigned short* __restrict__ zg) {
  __shared__ char lds[8192];
  int tid = threadIdx.x;
  int blk = blockIdx.x;                      // NE/16 blocks
  int er = tid >> 4, kc = tid & 15;          // edge-in-group, 16-float k-chunk
  int e = blk * 16 + er;
  int dst = ei[NE + e];
  const f32x4* ap = (const f32x4*)(ea + (size_t)e * DIM + kc * 16);
  const f32x4* xp = (const f32x4*)(x + (size_t)dst * DIM + kc * 16);
  int ks = kc >> 1, rqb = (kc & 1) * 2;
#pragma unroll
  for (int j = 0; j < 2; j++) {              // two 8-float halves
    f32x4 p0 = ap[j * 2 + 0] * xp[j * 2 + 0];
    f32x4 p1 = ap[j * 2 + 1] * xp[j * 2 + 1];
    unsigned int h[8];
    h[0] = f2bf(p0.x); h[1] = f2bf(p0.y); h[2] = f2bf(p0.z); h[3] = f2bf(p0.w);
    h[4] = f2bf(p1.x); h[5] = f2bf(p1.y); h[6] = f2bf(p1.z); h[7] = f2bf(p1.w);
    i32x4 o;
    o.x = (int)(h[0] | (h[1] << 16));
    o.y = (int)(h[2] | (h[3] << 16));
    o.z = (int)(h[4] | (h[5] << 16));
    o.w = (int)(h[6] | (h[7] << 16));
    *(i32x4*)(lds + ks * 1024 + (rqb + j) * 256 + er * 16) = o;
  }
  __syncthreads();
  // phase B: LDS is already in output order -> linear copy, coalesced stores
  int ks_o = tid >> 5, m = tid & 31;
  int bt = blk & 3;
  char* outp = (char*)zg + (size_t)(blk >> 2) * 65536 +
               (size_t)(ks_o * 4 + bt) * 1024 + m * 32;
  i32x4 v0 = *(i32x4*)(lds + tid * 32);
  i32x4 v1 = *(i32x4*)(lds + tid * 32 + 16);
  *(i32x4*)outp = v0;
  *(i32x4*)(outp + 16) = v1;
}

// ---------- q kernel (64-row tiles) ----------
__device__ __forceinline__ void gemm_tile(const unsigned short* zs,
                                          const unsigned short* wf,
                                          int lane, int wv, f32x4 (&acc)[4][4]) {
#pragma unroll 1
  for (int ksI = 0; ksI < 8; ksI++) {
    bf16x8 afr[4], bfr[4];
#pragma unroll
    for (int rt = 0; rt < 4; rt++) {
      int row = rt * 16 + (lane & 15);
      int k = ksI * 32 + (lane >> 4) * 8;
      int byteo = (row * 512 + k * 2) ^ ((row & 7) << 4);
      B8 u; u.i = *(const i32x4*)((const char*)zs + byteo);
      afr[rt] = u.b;
    }
#pragma unroll
    for (int ct = 0; ct < 4; ct++) {
      B8 u; u.i = ((const i32x4*)wf)[ksI * 1024 + (wv * 4 + ct) * 64 + lane];
      bfr[ct] = u.b;
    }
#pragma unroll
    for (int rt = 0; rt < 4; rt++)
#pragma unroll
      for (int ct = 0; ct < 4; ct++)
        acc[rt][ct] = __builtin_amdgcn_mfma_f32_16x16x32_bf16(afr[rt], bfr[ct], acc[rt][ct], 0, 0, 0);
  }
}

__global__ __launch_bounds__(256) void q_kernel(const float* __restrict__ x,
                                                const unsigned short* __restrict__ wf,
                                                float* __restrict__ q) {
  __shared__ unsigned short zs[64 * 256];
  int tid = threadIdx.x, lane = tid & 63, wv = tid >> 6;
  int r0 = blockIdx.x * 64;
  int dcol = lane * 4;
#pragma unroll 4
  for (int rr = 0; rr < 16; rr++) {
    int r = rr * 4 + wv;
    int row = r0 + r;
    f32x4 a = {0.f, 0.f, 0.f, 0.f};
    if (row < NN) a = *(const f32x4*)(x + (size_t)row * DIM + dcol);
    u16x4 z;
    z.x = f2bf(a.x); z.y = f2bf(a.y); z.z = f2bf(a.z); z.w = f2bf(a.w);
    int byteo = (r * 512 + dcol * 2) ^ ((r & 7) << 4);
    *(u16x4*)((char*)zs + byteo) = z;
  }
  __syncthreads();
  f32x4 acc[4][4];
#pragma unroll
  for (int rt = 0; rt < 4; rt++)
#pragma unroll
    for (int ct = 0; ct < 4; ct++) acc[rt][ct] = (f32x4){0.f, 0.f, 0.f, 0.f};
  gemm_tile(zs, wf, lane, wv, acc);
  int cq = lane & 15, rq = lane >> 4;
#pragma unroll
  for (int ct = 0; ct < 4; ct++) {
    int col = wv * 64 + ct * 16 + cq;
#pragma unroll
    for (int rt = 0; rt < 4; rt++) {
#pragma unroll
      for (int j = 0; j < 4; j++) {
        int row = r0 + rt * 16 + rq * 4 + j;
        if (row < NN) q[(size_t)row * DIM + col] = acc[rt][ct][j];
      }
    }
  }
}

// ---------- edge GEMM v4b: no LDS staging; ONE barrier (alias protection) ----------
// 8 waves; wave wv = head wv (32 channels) x 64 edges. Z frags read per-wave from
// zg (L2/L3-resident, lane-contiguous 1KB). Pass order v, k, e. edge_out writes
// alias this block's zg tile, so a single __syncthreads() after the last pass's
// MFMA loop (all Z reads complete) and before the edge_out stores prevents any
// wave overwriting Z that another wave still needs.
__global__ __launch_bounds__(512) void gemm_edge(
    const unsigned short* __restrict__ zg, const int* __restrict__ ei,
    const int* __restrict__ pos,
    const unsigned short* __restrict__ wfk, const unsigned short* __restrict__ wfv,
    const unsigned short* __restrict__ wfe, const float* __restrict__ be,
    const float* __restrict__ q, unsigned short* __restrict__ vws,
    float* __restrict__ sperm, float* __restrict__ edge_out) {
  int tid = threadIdx.x, lane = tid & 63, wv = tid >> 6;   // wv = head 0..7
  int rq = lane >> 4, cl = lane & 15;
  int e0 = blockIdx.x * 64;
  const i32x4* gz = (const i32x4*)((const char*)zg + (size_t)blockIdx.x * 65536);

  int sr4[4], pe4[4];
#pragma unroll
  for (int b = 0; b < 4; b++) {
    sr4[b] = ei[e0 + b * 16 + cl];
    pe4[b] = pos[e0 + b * 16 + cl];
  }

  const unsigned short* wfs[3] = {wfv, wfk, wfe};
  i32x4 wbuf[2][2];   // 2-slot ring, lead-1 weight frags (L2)
  i32x4 zbuf[2][4];   // 2-slot ring, lead-1 Z frags (L2/L3)
  f32x4 acc[2][4];

#define LOADW(S, SLOT)                                                         \
  {                                                                            \
    const unsigned short* wfp = wfs[(S) >> 3];                                 \
    _Pragma("unroll") for (int a = 0; a < 2; a++)                              \
        wbuf[SLOT][a] =                                                        \
            ((const i32x4*)wfp)[((S) & 7) * 1024 + (wv * 2 + a) * 64 + lane];  \
  }
#define LOADZ(S, SLOT)                                                         \
  {                                                                            \
    _Pragma("unroll") for (int b = 0; b < 4; b++)                              \
      zbuf[SLOT][b] = gz[(((S) & 7) * 4 + b) * 64 + lane];                     \
  }
#define GEMM_PASS(P)                                                           \
  _Pragma("unroll") for (int a = 0; a < 2; a++)                                \
      _Pragma("unroll") for (int b = 0; b < 4; b++)                            \
          acc[a][b] = (f32x4){0.f, 0.f, 0.f, 0.f};                             \
  _Pragma("unroll") for (int ks = 0; ks < 8; ks++) {                           \
    const int step = (P) * 8 + ks;                                             \
    if (step + 1 < 24) { LOADW(step + 1, (step + 1) & 1);                      \
                         LOADZ(step + 1, (step + 1) & 1); }                    \
    _Pragma("unroll") for (int a = 0; a < 2; a++) {                            \
      B8 w; w.i = wbuf[step & 1][a];                                           \
      _Pragma("unroll") for (int b = 0; b < 4; b++) {                          \
        B8 z; z.i = zbuf[step & 1][b];                                         \
        acc[a][b] = __builtin_amdgcn_mfma_f32_16x16x32_bf16(w.b, z.b,          \
                                                            acc[a][b], 0, 0, 0); \
      }                                                                        \
    }                                                                          \
  }

  LOADW(0, 0); LOADZ(0, 0);

  // ---- pass 0: v = Z @ Wv^T -> bf16 ws ----
  GEMM_PASS(0)
#pragma unroll
  for (int a = 0; a < 2; a++) {
    int ch = wv * 32 + a * 16 + rq * 4;
#pragma unroll
    for (int b = 0; b < 4; b++) {
      int edge = b * 16 + cl;
      u16x4 o;
      o.x = f2bf(acc[a][b][0]); o.y = f2bf(acc[a][b][1]);
      o.z = f2bf(acc[a][b][2]); o.w = f2bf(acc[a][b][3]);
      *(u16x4*)(vws + (size_t)(e0 + edge) * DIM + ch) = o;
    }
  }

  // ---- pass 1: k = Z @ Wk^T; scores for head wv, CSR-permuted ----
  GEMM_PASS(1)
#pragma unroll
  for (int b = 0; b < 4; b++) {
    const float* qp = q + (size_t)sr4[b] * DIM + wv * 32 + rq * 4;
    f32x4 q0 = *(const f32x4*)(qp);
    f32x4 q1 = *(const f32x4*)(qp + 16);
    float s = acc[0][b][0] * q0[0] + acc[0][b][1] * q0[1] +
              acc[0][b][2] * q0[2] + acc[0][b][3] * q0[3] +
              acc[1][b][0] * q1[0] + acc[1][b][1] * q1[1] +
              acc[1][b][2] * q1[2] + acc[1][b][3] * q1[3];
    s += __shfl_xor(s, 16);
    s += __shfl_xor(s, 32);
    if (lane < 16) {
      sperm[(size_t)pe4[b] * 8 + wv] = s * 0.17677669529663687f;
    }
  }

  // ---- pass 2: edge_out = Z @ We^T + be ----
  GEMM_PASS(2)
  // All Z reads of every wave completed inside GEMM_PASS(2); edge_out stores
  // below overwrite this block's zg tile -> must wait for all waves first.
  __syncthreads();
#pragma unroll
  for (int a = 0; a < 2; a++) {
    int ch = wv * 32 + a * 16 + rq * 4;
    f32x4 bias = *(const f32x4*)(be + ch);
#pragma unroll
    for (int b = 0; b < 4; b++) {
      int edge = b * 16 + cl;
      f32x4 o = acc[a][b] + bias;
      *(f32x4*)(edge_out + (size_t)(e0 + edge) * DIM + ch) = o;
    }
  }
#undef LOADW
#undef LOADZ
#undef GEMM_PASS
}

// ---------- CSR build ----------
__global__ __launch_bounds__(256) void count_kernel(const int* __restrict__ ei,
                                                    int* __restrict__ counts) {
  int e = blockIdx.x * 256 + threadIdx.x;
  if (e < NE) atomicAdd(&counts[ei[e]], 1);
}

// One block, per-thread 79-element chunk + shfl wave scan.
__global__ __launch_bounds__(256) void scan_kernel(const int* __restrict__ counts,
                                                   int* __restrict__ offs,
                                                   int* __restrict__ cursor) {
  const int CH = 79;                      // 256*79 = 20224 >= NN
  int tid = threadIdx.x;
  int lane = tid & 63, wv = tid >> 6;
  int b0 = tid * CH;
  int sum = 0;
  for (int j = 0; j < CH; j++) {
    int i = b0 + j;
    if (i < NN) sum += counts[i];
  }
  int pre = sum;
  for (int d = 1; d < 64; d <<= 1) {
    int t = __shfl_up(pre, d);
    if (lane >= d) pre += t;
  }
  __shared__ int wsum[4];
  if (lane == 63) wsum[wv] = pre;
  __syncthreads();
  int base = 0;
  for (int w = 0; w < wv; w++) base += wsum[w];
  int running = base + pre - sum;         // exclusive prefix at b0
  for (int j = 0; j < CH; j++) {
    int i = b0 + j;
    if (i < NN) {
      offs[i] = running;
      cursor[i] = running;
      running += counts[i];
    }
  }
  if (tid == 255) offs[NN] = running;
}

__global__ __launch_bounds__(256) void fill_kernel(const int* __restrict__ ei,
                                                   int* __restrict__ cursor,
                                                   int* __restrict__ eids,
                                                   int* __restrict__ pos) {
  int e = blockIdx.x * 256 + threadIdx.x;
  if (e < NE) {
    int p = atomicAdd(&cursor[ei[e]], 1);
    eids[p] = e;
    pos[e] = p;
  }
}

// One wave per src node: online softmax; scores sequential (permuted), v gathered
// with a 2-stage pipeline.
__global__ __launch_bounds__(256) void node_kernel(const int* __restrict__ offs,
                                                   const int* __restrict__ eids,
                                                   const float* __restrict__ sperm,
                                                   const unsigned short* __restrict__ vws,
                                                   float* __restrict__ out) {
  int tid = threadIdx.x;
  int n = blockIdx.x * 4 + (tid >> 6);
  int lane = tid & 63, h = lane >> 3;
  int o0 = offs[n], deg = offs[n + 1] - o0;
  float m = -INFINITY, s = 0.f;
  float a0 = 0.f, a1 = 0.f, a2 = 0.f, a3 = 0.f;
  int e = (deg > 0) ? eids[o0] : 0;
  u16x4 v = *(const u16x4*)(vws + (size_t)e * DIM + lane * 4);
  for (int i = 0; i < deg; i++) {
    int en = (i + 1 < deg) ? eids[o0 + i + 1] : e;
    u16x4 vn = *(const u16x4*)(vws + (size_t)en * DIM + lane * 4);
    float sc = sperm[(size_t)(o0 + i) * 8 + h];
    float mn = fmaxf(m, sc);
    float scale = __expf(m - mn);
    float p = __expf(sc - mn);
    s = s * scale + p;
    m = mn;
    a0 = a0 * scale + p * bf2f(v.x);
    a1 = a1 * scale + p * bf2f(v.y);
    a2 = a2 * scale + p * bf2f(v.z);
    a3 = a3 * scale + p * bf2f(v.w);
    v = vn;
  }
  float inv = 1.f / (s + 1e-16f);
  f32x4 o;
  o.x = a0 * inv; o.y = a1 * inv; o.z = a2 * inv; o.w = a3 * inv;
  *(f32x4*)(out + (size_t)n * DIM + lane * 4) = o;
}

extern "C" void kernel_launch(void* const* d_in, const int* in_sizes, int n_in,
                              void* d_out, int out_size, void* d_ws, size_t ws_size,
                              hipStream_t stream) {
  const float* x = (const float*)d_in[0];
  const int* ei = (const int*)d_in[1];
  const float* ea = (const float*)d_in[2];
  const float* Wq = (const float*)d_in[3];
  const float* Wk = (const float*)d_in[4];
  const float* Wv = (const float*)d_in[5];
  const float* We = (const float*)d_in[6];
  const float* be = (const float*)d_in[7];

  float* out = (float*)d_out;                       // [NN, 256]
  float* edge_out = out + (size_t)NN * DIM;         // [NE, 256] f32
  unsigned short* zg = (unsigned short*)edge_out;   // Z packed: tile t -> 32KB at t*64KB
  float* q = out;                                   // q scratch (overwritten by node_kernel)

  char* ws = (char*)d_ws;
  unsigned short* wfq = (unsigned short*)(ws + 0);
  unsigned short* wfk = (unsigned short*)(ws + 131072);
  unsigned short* wfv = (unsigned short*)(ws + 262144);
  unsigned short* wfe = (unsigned short*)(ws + 393216);
  unsigned short* vws = (unsigned short*)(ws + 524288);            // [NE,256] bf16
  float* sperm = (float*)(ws + 524288 + 163840000);                // [NE,8] f32, CSR order
  int* counts = (int*)(ws + 524288 + 163840000 + 10240000);
  int* offs   = (int*)(ws + 524288 + 163840000 + 10240000 + 80000);
  int* cursor = (int*)(ws + 524288 + 163840000 + 10240000 + 160016);
  int* eids   = (int*)(ws + 524288 + 163840000 + 10240000 + 240016);
  int* pos    = (int*)(ws + 524288 + 163840000 + 10240000 + 240016 + 1280000);

  hipMemsetAsync(counts, 0, NN * sizeof(int), stream);

  pack_w<<<32, 256, 0, stream>>>(Wq, wfq);
  pack_w<<<32, 256, 0, stream>>>(Wk, wfk);
  pack_w<<<32, 256, 0, stream>>>(Wv, wfv);
  pack_w<<<32, 256, 0, stream>>>(We, wfe);

  zprep<<<NE / 16, 256, 0, stream>>>(x, ei, ea, zg);

  count_kernel<<<(NE + 255) / 256, 256, 0, stream>>>(ei, counts);
  scan_kernel<<<1, 256, 0, stream>>>(counts, offs, cursor);
  fill_kernel<<<(NE + 255) / 256, 256, 0, stream>>>(ei, cursor, eids, pos);

  q_kernel<<<(NN + 63) / 64, 256, 0, stream>>>(x, wfq, q);

  gemm_edge<<<NE / 64, 512, 0, stream>>>(zg, ei, pos, wfk, wfv, wfe, be, q,
                                         vws, sperm, edge_out);

  node_kernel<<<NN / 4, 256, 0, stream>>>(offs, eids, sperm, vws, out);
}